// Round 8
// baseline (79.138 us; speedup 1.0000x reference)
//
#include <hip/hip_runtime.h>
#include <cstddef>

#define B_ 2
#define C_ 32
#define CP 33
#define W_ 256
#define H_ 256
#define X_ 512
#define Y_ 512

typedef __bf16 bf16x8 __attribute__((ext_vector_type(8)));
typedef __bf16 bf16x4 __attribute__((ext_vector_type(4)));
typedef float  f32x4  __attribute__((ext_vector_type(4)));

#define AS1 __attribute__((address_space(1)))
#define AS3 __attribute__((address_space(3)))

__device__ __forceinline__ void gload16_lds(const void* g, void* l) {
    // async global->LDS, 16B/lane, LDS dest = wave-uniform base + lane*16
    __builtin_amdgcn_global_load_lds((const AS1 void*)g, (AS3 void*)l, 16, 0, 0);
}

// ws layout (bf16):
//   wlonT [B][X][W], wlatT [B][Y][H], wt33 [B][CP][W][H], U_T [B][CP][Y][W]

// ---------------- prep: bf16 tables ----------------
__global__ __launch_bounds__(256) void prep_kernel(
    const float* __restrict__ xin_lon, const float* __restrict__ xin_lat,
    const float* __restrict__ xout_lon, const float* __restrict__ xout_lat,
    const float* __restrict__ init_ls, const float* __restrict__ wt,
    __bf16* __restrict__ wlonT, __bf16* __restrict__ wlatT,
    __bf16* __restrict__ wt33)
{
    const int NLON = B_ * X_ * W_;
    const int NLAT = B_ * Y_ * H_;
    int t = blockIdx.x * 256 + threadIdx.x;
    float ls = init_ls[0];
    float cc = -0.5f / (ls * ls);
    if (t < NLON) {
        int b = t / (X_ * W_);
        int r = t - b * (X_ * W_);
        int x = r >> 8;
        int w = r & (W_ - 1);
        float d = xin_lon[b * W_ + w] - xout_lon[b * X_ + x];
        wlonT[t] = (__bf16)__expf(cc * d * d);
    } else if (t < NLON + NLAT) {
        int j = t - NLON;
        int b = j / (Y_ * H_);
        int r = j - b * (Y_ * H_);
        int y = r >> 8;
        int h = r & (H_ - 1);
        float d = xin_lat[b * H_ + h] - xout_lat[b * Y_ + y];
        wlatT[j] = (__bf16)__expf(cc * d * d);
    } else {
        int j = t - (NLON + NLAT);
        int o = j * 4;
        int b = o / (CP * W_ * H_);
        int r = o - b * (CP * W_ * H_);
        int co = r / (W_ * H_);
        int p = r & (W_ * H_ - 1);
        float4 v;
        bf16x4 ov;
        if (co == 0) {
            v = *(const float4*)&wt[((size_t)b * C_) * (W_ * H_) + p];
            ov[0] = (__bf16)((v.x != v.x) ? 0.f : 1.f);
            ov[1] = (__bf16)((v.y != v.y) ? 0.f : 1.f);
            ov[2] = (__bf16)((v.z != v.z) ? 0.f : 1.f);
            ov[3] = (__bf16)((v.w != v.w) ? 0.f : 1.f);
        } else {
            v = *(const float4*)&wt[((size_t)b * C_ + (co - 1)) * (W_ * H_) + p];
            ov[0] = (__bf16)((v.x != v.x) ? 0.f : v.x);
            ov[1] = (__bf16)((v.y != v.y) ? 0.f : v.y);
            ov[2] = (__bf16)((v.z != v.z) ? 0.f : v.z);
            ov[3] = (__bf16)((v.w != v.w) ? 0.f : v.w);
        }
        *(bf16x4*)&wt33[o] = ov;
    }
}

// ---------------- batched 128x128xK256 MFMA GEMM tile ----------------
// C[m][n] = sum_k A[m][k] * B[n][k]; operands row-major, row stride 256 (=K).
// Staged per-BK=32 via global_load_lds in fragment-linear order, double-
// buffered, counted vmcnt(4), raw s_barrier. 4 waves (2m x 2n), 64x64 each.
// Epilogues transpose through LDS (tile buffers are dead) for coalesced
// 256B-span stores — round-7 lesson: 8B/64B scattered stores dominated.
// MODE 0: A=wt33 panel, B=wlatT,   out = U_T (bf16, [y][w])
// MODE 1: A=wlonT,      B=U_T ch0, out = out ch0 raw (= density ee)
// MODE 2: A=wlonT,      B=U_T ch,  out = out ch / clip(out ch0)
template<int MODE>
__global__ __launch_bounds__(256, 2) void gemm_tile(
    const __bf16* __restrict__ wt33, const __bf16* __restrict__ wlonT,
    const __bf16* __restrict__ wlatT, __bf16* __restrict__ U_T,
    float* __restrict__ out)
{
    constexpr int K_ = 256;
    __shared__ union SM {
        struct { __bf16 A[2][4096]; __bf16 Bt[2][4096]; } t;  // 32 KB
        float  tf[4][2176];   // 4 waves x 32 x 68 (f32 transpose, padded)
        __bf16 th[17408];     // 128 x 136 (bf16 transpose, padded)
    } sm;

    const int t    = threadIdx.x;
    const int lane = t & 63;
    const int wave = t >> 6;
    const int wm   = wave >> 1, wn = wave & 1;
    const int lrow = lane & 15, lkg = lane >> 4;

    const int bid = blockIdx.x;
    int bb, chh, mtile, ntile;
    const __bf16 *Abase, *Bbase;
    if constexpr (MODE == 0) {
        int p = bid >> 3, tile = bid & 7;
        mtile = tile >> 2; ntile = tile & 3;       // 2 x 4 tiles (W x Y)
        bb = (p >= CP) ? 1 : 0; chh = p - bb * CP;
        Abase = wt33 + (size_t)p * (W_ * H_) + (size_t)mtile * 128 * H_;
        Bbase = wlatT + (size_t)bb * (Y_ * H_) + (size_t)ntile * 128 * H_;
    } else if constexpr (MODE == 1) {
        bb = bid >> 4; int tile = bid & 15;
        mtile = tile >> 2; ntile = tile & 3;       // 4 x 4 tiles (X x Y)
        chh = 0;
        Abase = wlonT + (size_t)bb * (X_ * W_) + (size_t)mtile * 128 * W_;
        Bbase = U_T + (size_t)(bb * CP) * (Y_ * W_) + (size_t)ntile * 128 * W_;
    } else {
        int xcd = bid & 7, k = bid >> 3;           // 8 channels per XCD
        int g = k >> 4, tile = k & 15;
        mtile = tile >> 2; ntile = tile & 3;
        int bc = xcd * 8 + g;
        bb = bc >> 5; chh = (bc & 31) + 1;
        Abase = wlonT + (size_t)bb * (X_ * W_) + (size_t)mtile * 128 * W_;
        Bbase = U_T + (size_t)(bb * CP + chh) * (Y_ * W_) + (size_t)ntile * 128 * W_;
    }

    // staging decode: chunk c = i*256 + t covers a 128x32 tile in
    // fragment-linear order: row = (c>>8)*64 + ((c>>6)&3)*16 + (c&15),
    // k-subgroup = (c>>4)&3. Reads back as frag[g] at [(g*64+lane)*8].
    int rowoff[2], ldsoff[2];
#pragma unroll
    for (int i = 0; i < 2; ++i) {
        int c = i * 256 + t;
        int row  = ((c >> 8) << 6) + (((c >> 6) & 3) << 4) + (c & 15);
        int col8 = (c >> 4) & 3;
        rowoff[i] = row * K_ + col8 * 8;
        ldsoff[i] = (i * 256 + wave * 64) * 8;     // wave-uniform LDS base
    }

    auto stage = [&](int buf, int kt) {
#pragma unroll
        for (int i = 0; i < 2; ++i) {
            gload16_lds((const void*)(Abase + rowoff[i] + kt * 32),
                        (void*)&sm.t.A[buf][ldsoff[i]]);
            gload16_lds((const void*)(Bbase + rowoff[i] + kt * 32),
                        (void*)&sm.t.Bt[buf][ldsoff[i]]);
        }
    };

    f32x4 acc[4][4] = {};
    stage(0, 0);
#pragma unroll
    for (int kt = 0; kt < 8; ++kt) {
        const int buf = kt & 1;
        if (kt < 7) {
            stage(buf ^ 1, kt + 1);
            asm volatile("s_waitcnt vmcnt(4)" ::: "memory");  // cur tile landed
        } else {
            asm volatile("s_waitcnt vmcnt(0)" ::: "memory");
        }
        __builtin_amdgcn_s_barrier();
        bf16x8 af[4], bf[4];
#pragma unroll
        for (int mt = 0; mt < 4; ++mt)
            af[mt] = *(const bf16x8*)&sm.t.A[buf][((wm * 4 + mt) * 64 + lane) * 8];
#pragma unroll
        for (int nt = 0; nt < 4; ++nt)
            bf[nt] = *(const bf16x8*)&sm.t.Bt[buf][((wn * 4 + nt) * 64 + lane) * 8];
#pragma unroll
        for (int mt = 0; mt < 4; ++mt)
#pragma unroll
            for (int nt = 0; nt < 4; ++nt)
                acc[mt][nt] = __builtin_amdgcn_mfma_f32_16x16x32_bf16(
                    af[mt], bf[nt], acc[mt][nt], 0, 0, 0);
        __builtin_amdgcn_sched_barrier(0);   // pin reads+MFMAs before barrier
        __builtin_amdgcn_s_barrier();        // buf safe to overwrite next iter
    }

    // ---- epilogue ----
    if constexpr (MODE == 0) {
        // block-cooperative bf16 transpose -> U_T rows [y][w], 256B spans
#pragma unroll
        for (int mt = 0; mt < 4; ++mt)
#pragma unroll
            for (int nt = 0; nt < 4; ++nt) {
                int yloc = wn * 64 + nt * 16 + lrow;
                int wloc = wm * 64 + mt * 16 + lkg * 4;
                f32x4 c = acc[mt][nt];
                bf16x4 v4;
                v4[0] = (__bf16)c[0]; v4[1] = (__bf16)c[1];
                v4[2] = (__bf16)c[2]; v4[3] = (__bf16)c[3];
                *(bf16x4*)&sm.th[yloc * 136 + wloc] = v4;
            }
        __syncthreads();
        __bf16* up = U_T + (size_t)(bb * CP + chh) * (Y_ * W_);
#pragma unroll
        for (int it = 0; it < 8; ++it) {
            int c2 = it * 256 + t;
            int y = c2 >> 4, w8 = c2 & 15;
            bf16x8 v = *(const bf16x8*)&sm.th[y * 136 + w8 * 8];
            *(bf16x8*)&up[(size_t)(ntile * 128 + y) * W_ + mtile * 128 + w8 * 8] = v;
        }
    } else {
        // per-wave f32 transpose (two 32x64 halves), coalesced f32x4 stores
        const int mg0 = mtile * 128 + wm * 64;     // x origin of wave tile
        const int ng0 = ntile * 128 + wn * 64;     // y origin of wave tile
        float* TW = &sm.tf[wave][0];               // 32 x 68 floats
        const float* ch0 = out + (size_t)bb * CP * (X_ * Y_);
        float* outc = out + ((size_t)bb * CP + chh) * (size_t)(X_ * Y_);
#pragma unroll
        for (int h = 0; h < 2; ++h) {
#pragma unroll
            for (int m2 = 0; m2 < 2; ++m2) {
                int mt = h * 2 + m2;
#pragma unroll
                for (int nt = 0; nt < 4; ++nt) {
                    f32x4 c = acc[mt][nt];
#pragma unroll
                    for (int r = 0; r < 4; ++r)
                        TW[(m2 * 16 + lkg * 4 + r) * 68 + nt * 16 + lrow] = c[r];
                }
            }
            asm volatile("s_waitcnt lgkmcnt(0)" ::: "memory");
            __builtin_amdgcn_sched_barrier(0);
#pragma unroll
            for (int j = 0; j < 8; ++j) {
                int xl = j * 4 + lkg;
                f32x4 v = *(const f32x4*)&TW[xl * 68 + lrow * 4];
                int xg = mg0 + h * 32 + xl;
                int yg = ng0 + lrow * 4;
                if constexpr (MODE == 2) {
                    f32x4 e = *(const f32x4*)&ch0[(size_t)xg * Y_ + yg];
#pragma unroll
                    for (int r = 0; r < 4; ++r)
                        v[r] = v[r] / fminf(fmaxf(e[r], 1e-6f), 1e5f);
                }
                *(f32x4*)&outc[(size_t)xg * Y_ + yg] = v;
            }
            // WAR: half-1 LDS writes must not pass half-0 reads
            asm volatile("s_waitcnt lgkmcnt(0)" ::: "memory");
            __builtin_amdgcn_sched_barrier(0);
        }
    }
}

extern "C" void kernel_launch(void* const* d_in, const int* in_sizes, int n_in,
                              void* d_out, int out_size, void* d_ws, size_t ws_size,
                              hipStream_t stream)
{
    const float* xin_lon  = (const float*)d_in[0];
    const float* xin_lat  = (const float*)d_in[1];
    const float* wt       = (const float*)d_in[2];
    const float* xout_lon = (const float*)d_in[3];
    const float* xout_lat = (const float*)d_in[4];
    const float* init_ls  = (const float*)d_in[5];
    float* out = (float*)d_out;

    __bf16* wlonT = (__bf16*)d_ws;
    __bf16* wlatT = wlonT + (size_t)B_ * X_ * W_;
    __bf16* wt33  = wlatT + (size_t)B_ * Y_ * H_;
    __bf16* U_T   = wt33 + (size_t)B_ * CP * W_ * H_;

    prep_kernel<<<6272, 256, 0, stream>>>(xin_lon, xin_lat, xout_lon, xout_lat,
                                          init_ls, wt, wlonT, wlatT, wt33);
    gemm_tile<0><<<B_ * CP * 8, 256, 0, stream>>>(wt33, wlonT, wlatT, U_T, out);
    gemm_tile<1><<<B_ * 16,     256, 0, stream>>>(wt33, wlonT, wlatT, U_T, out);
    gemm_tile<2><<<1024,        256, 0, stream>>>(wt33, wlonT, wlatT, U_T, out);
}

// Round 9
// 62.322 us; speedup vs baseline: 1.2698x; 1.2698x over previous
//
#include <hip/hip_runtime.h>
#include <cstddef>

#define B_ 2
#define C_ 32
#define CP 33
#define W_ 256
#define H_ 256
#define X_ 512
#define Y_ 512

typedef __bf16 bf16x8 __attribute__((ext_vector_type(8)));
typedef __bf16 bf16x4 __attribute__((ext_vector_type(4)));
typedef float  f32x4  __attribute__((ext_vector_type(4)));

#define AS1 __attribute__((address_space(1)))
#define AS3 __attribute__((address_space(3)))

__device__ __forceinline__ void gload16_lds(const void* g, void* l) {
    // async global->LDS, 16B/lane, LDS dest = wave-uniform base + lane*16
    __builtin_amdgcn_global_load_lds((const AS1 void*)g, (AS3 void*)l, 16, 0, 0);
}

// ws layout (bf16):
//   wlonT [B][X][W], wlatT [B][Y][H], wt33 [B][CP][W][H], U_T [B][CP][Y][W]

// ---------------- prep: bf16 tables ----------------
__global__ __launch_bounds__(256) void prep_kernel(
    const float* __restrict__ xin_lon, const float* __restrict__ xin_lat,
    const float* __restrict__ xout_lon, const float* __restrict__ xout_lat,
    const float* __restrict__ init_ls, const float* __restrict__ wt,
    __bf16* __restrict__ wlonT, __bf16* __restrict__ wlatT,
    __bf16* __restrict__ wt33)
{
    const int NLON = B_ * X_ * W_;
    const int NLAT = B_ * Y_ * H_;
    int t = blockIdx.x * 256 + threadIdx.x;
    float ls = init_ls[0];
    float cc = -0.5f / (ls * ls);
    if (t < NLON) {
        int b = t / (X_ * W_);
        int r = t - b * (X_ * W_);
        int x = r >> 8;
        int w = r & (W_ - 1);
        float d = xin_lon[b * W_ + w] - xout_lon[b * X_ + x];
        wlonT[t] = (__bf16)__expf(cc * d * d);
    } else if (t < NLON + NLAT) {
        int j = t - NLON;
        int b = j / (Y_ * H_);
        int r = j - b * (Y_ * H_);
        int y = r >> 8;
        int h = r & (H_ - 1);
        float d = xin_lat[b * H_ + h] - xout_lat[b * Y_ + y];
        wlatT[j] = (__bf16)__expf(cc * d * d);
    } else {
        int j = t - (NLON + NLAT);
        int o = j * 4;
        int b = o / (CP * W_ * H_);
        int r = o - b * (CP * W_ * H_);
        int co = r / (W_ * H_);
        int p = r & (W_ * H_ - 1);
        float4 v;
        bf16x4 ov;
        if (co == 0) {
            v = *(const float4*)&wt[((size_t)b * C_) * (W_ * H_) + p];
            ov[0] = (__bf16)((v.x != v.x) ? 0.f : 1.f);
            ov[1] = (__bf16)((v.y != v.y) ? 0.f : 1.f);
            ov[2] = (__bf16)((v.z != v.z) ? 0.f : 1.f);
            ov[3] = (__bf16)((v.w != v.w) ? 0.f : 1.f);
        } else {
            v = *(const float4*)&wt[((size_t)b * C_ + (co - 1)) * (W_ * H_) + p];
            ov[0] = (__bf16)((v.x != v.x) ? 0.f : v.x);
            ov[1] = (__bf16)((v.y != v.y) ? 0.f : v.y);
            ov[2] = (__bf16)((v.z != v.z) ? 0.f : v.z);
            ov[3] = (__bf16)((v.w != v.w) ? 0.f : v.w);
        }
        *(bf16x4*)&wt33[o] = ov;
    }
}

// ---------------- stage 1: U_T = (wt33 x wlatT^T)^T ----------------
// 128x128xK256 tile; both operands staged per-BK=32 via global_load_lds in
// fragment-linear order; double-buffered; counted vmcnt(4); raw s_barrier.
// Epilogue transposes through LDS -> U_T[b][ch][y][w] with 256B-span writes.
__global__ __launch_bounds__(256, 2) void gemm_u(
    const __bf16* __restrict__ wt33, const __bf16* __restrict__ wlatT,
    __bf16* __restrict__ U_T)
{
    constexpr int K_ = 256;
    __shared__ union SM {
        struct { __bf16 A[2][4096]; __bf16 Bt[2][4096]; } t;  // 32 KB
        __bf16 th[17408];     // 128 x 136 (bf16 transpose, padded)
    } sm;

    const int t    = threadIdx.x;
    const int lane = t & 63;
    const int wave = t >> 6;
    const int wm   = wave >> 1, wn = wave & 1;
    const int lrow = lane & 15, lkg = lane >> 4;

    const int bid = blockIdx.x;
    int p = bid >> 3, tile = bid & 7;
    int mtile = tile >> 2, ntile = tile & 3;       // 2 x 4 tiles (W x Y)
    int bb = (p >= CP) ? 1 : 0, chh = p - bb * CP;
    const __bf16* Abase = wt33 + (size_t)p * (W_ * H_) + (size_t)mtile * 128 * H_;
    const __bf16* Bbase = wlatT + (size_t)bb * (Y_ * H_) + (size_t)ntile * 128 * H_;

    int rowoff[2], ldsoff[2];
#pragma unroll
    for (int i = 0; i < 2; ++i) {
        int c = i * 256 + t;
        int row  = ((c >> 8) << 6) + (((c >> 6) & 3) << 4) + (c & 15);
        int col8 = (c >> 4) & 3;
        rowoff[i] = row * K_ + col8 * 8;
        ldsoff[i] = (i * 256 + wave * 64) * 8;
    }

    auto stage = [&](int buf, int kt) {
#pragma unroll
        for (int i = 0; i < 2; ++i) {
            gload16_lds((const void*)(Abase + rowoff[i] + kt * 32),
                        (void*)&sm.t.A[buf][ldsoff[i]]);
            gload16_lds((const void*)(Bbase + rowoff[i] + kt * 32),
                        (void*)&sm.t.Bt[buf][ldsoff[i]]);
        }
    };

    f32x4 acc[4][4] = {};
    stage(0, 0);
#pragma unroll
    for (int kt = 0; kt < 8; ++kt) {
        const int buf = kt & 1;
        if (kt < 7) {
            stage(buf ^ 1, kt + 1);
            asm volatile("s_waitcnt vmcnt(4)" ::: "memory");
        } else {
            asm volatile("s_waitcnt vmcnt(0)" ::: "memory");
        }
        __builtin_amdgcn_s_barrier();
        bf16x8 af[4], bf[4];
#pragma unroll
        for (int mt = 0; mt < 4; ++mt)
            af[mt] = *(const bf16x8*)&sm.t.A[buf][((wm * 4 + mt) * 64 + lane) * 8];
#pragma unroll
        for (int nt = 0; nt < 4; ++nt)
            bf[nt] = *(const bf16x8*)&sm.t.Bt[buf][((wn * 4 + nt) * 64 + lane) * 8];
#pragma unroll
        for (int mt = 0; mt < 4; ++mt)
#pragma unroll
            for (int nt = 0; nt < 4; ++nt)
                acc[mt][nt] = __builtin_amdgcn_mfma_f32_16x16x32_bf16(
                    af[mt], bf[nt], acc[mt][nt], 0, 0, 0);
        __builtin_amdgcn_sched_barrier(0);
        __builtin_amdgcn_s_barrier();
    }

    // block-cooperative bf16 transpose -> U_T rows [y][w], 256B spans
#pragma unroll
    for (int mt = 0; mt < 4; ++mt)
#pragma unroll
        for (int nt = 0; nt < 4; ++nt) {
            int yloc = wn * 64 + nt * 16 + lrow;
            int wloc = wm * 64 + mt * 16 + lkg * 4;
            f32x4 c = acc[mt][nt];
            bf16x4 v4;
            v4[0] = (__bf16)c[0]; v4[1] = (__bf16)c[1];
            v4[2] = (__bf16)c[2]; v4[3] = (__bf16)c[3];
            *(bf16x4*)&sm.th[yloc * 136 + wloc] = v4;
        }
    __syncthreads();
    __bf16* up = U_T + (size_t)(bb * CP + chh) * (Y_ * W_);
#pragma unroll
    for (int it = 0; it < 8; ++it) {
        int c2 = it * 256 + t;
        int y = c2 >> 4, w8 = c2 & 15;
        bf16x8 v = *(const bf16x8*)&sm.th[y * 136 + w8 * 8];
        *(bf16x8*)&up[(size_t)(ntile * 128 + y) * W_ + mtile * 128 + w8 * 8] = v;
    }
}

// ---------------- stage 2 fused: all 33 channels + divide, one kernel ----
// Per block: (b, x-tile 64, y-tile 128, channel group of 4).
//   B = wlonT x-panel (n = x), LDS-RESIDENT 32 KB, staged once.
//   A = U_T y-panel (m = y), streamed per BK=32 through a 4-slot ring
//       (prefetch 2 kt ahead, counted vmcnt(4)), over 5 passes:
//       pass 0 = ch0 (density) -> rec = 1/clip kept in registers;
//       passes 1..4 = this group's channels, stored as acc*rec.
// Operand-role swap makes C row = y => each C-fragment reg quad is 4
// consecutive y at fixed x -> direct coalesced f32x4 stores, NO transpose.
__global__ __launch_bounds__(256, 2) void stage2_fused(
    const __bf16* __restrict__ wlonT, const __bf16* __restrict__ U_T,
    float* __restrict__ out)
{
    __shared__ __bf16 Blon[16384];      // 32 KB resident x-panel, frag-linear
    __shared__ __bf16 Ast[4][4096];     // 32 KB: 4-slot ring, 8 KB per kt

    const int t = threadIdx.x, lane = t & 63, wave = t >> 6;
    const int lrow = lane & 15, lkg = lane >> 4;
    const int wm = wave >> 1, wn = wave & 1;

    const int bid  = blockIdx.x;
    const int xcd  = bid & 7, r = bid >> 3;        // r: 0..63
    const int pair = r >> 5, rem = r & 31;
    const int yt   = rem >> 3, g = rem & 7;
    const int bxt  = xcd * 2 + pair;               // 0..15: same (b,xt) per XCD
    const int b    = bxt >> 3, xt = bxt & 7;
    const int x0   = xt * 64, y0 = yt * 128;

    const __bf16* lonp = wlonT + ((size_t)b * X_ + x0) * W_;
    const __bf16* Apan[5];
#pragma unroll
    for (int j = 0; j < 5; ++j) {
        int ch = (j == 0) ? 0 : (g * 4 + j);
        Apan[j] = U_T + (size_t)(b * CP + ch) * (Y_ * W_) + (size_t)y0 * W_;
    }

    // resident B: frag f = kt*4 + nG; staged as (i=kt, nG=wave)
    {
        const int srcoff = (wave * 16 + lrow) * W_ + lkg * 8;
#pragma unroll
        for (int i = 0; i < 8; ++i)
            gload16_lds((const void*)(lonp + srcoff + i * 32),
                        (void*)&Blon[(i * 4 + wave) * 512]);
    }
    // A stream: per kt 8 frags (mG = j*4+wave), 2 issues/thread
    auto stageA = [&](int slot, const __bf16* pan, int kt) {
#pragma unroll
        for (int j = 0; j < 2; ++j) {
            const __bf16* src = pan + (size_t)((j * 4 + wave) * 16 + lrow) * W_
                                + kt * 32 + lkg * 8;
            gload16_lds((const void*)src, (void*)&Ast[slot][(j * 4 + wave) * 512]);
        }
    };

    stageA(0, Apan[0], 0);
    stageA(1, Apan[0], 1);

    f32x4 rec[4][2];
#pragma unroll
    for (int p = 0; p < 5; ++p) {
        f32x4 acc[4][2] = {};
#pragma unroll
        for (int kt = 0; kt < 8; ++kt) {
            const int s = p * 8 + kt;
            const int slot = s & 3;
            if (s < 38) {
                const int s2 = s + 2;
                stageA(slot ^ 2, Apan[s2 >> 3], s2 & 7);
                asm volatile("s_waitcnt vmcnt(4)" ::: "memory");
            } else if (s == 38) {
                asm volatile("s_waitcnt vmcnt(2)" ::: "memory");
            } else {
                asm volatile("s_waitcnt vmcnt(0)" ::: "memory");
            }
            __builtin_amdgcn_s_barrier();
            bf16x8 af[4], bfv[2];
#pragma unroll
            for (int mt = 0; mt < 4; ++mt)
                af[mt] = *(const bf16x8*)&Ast[slot][((wm * 4 + mt) * 64 + lane) * 8];
#pragma unroll
            for (int nt = 0; nt < 2; ++nt)
                bfv[nt] = *(const bf16x8*)&Blon[((kt * 4 + wn * 2 + nt) * 64 + lane) * 8];
#pragma unroll
            for (int mt = 0; mt < 4; ++mt)
#pragma unroll
                for (int nt = 0; nt < 2; ++nt)
                    acc[mt][nt] = __builtin_amdgcn_mfma_f32_16x16x32_bf16(
                        af[mt], bfv[nt], acc[mt][nt], 0, 0, 0);
            __builtin_amdgcn_sched_barrier(0);
            __builtin_amdgcn_s_barrier();
        }

        if (p == 0) {
#pragma unroll
            for (int mt = 0; mt < 4; ++mt)
#pragma unroll
                for (int nt = 0; nt < 2; ++nt) {
                    f32x4 c = acc[mt][nt], q;
#pragma unroll
                    for (int rr = 0; rr < 4; ++rr)
                        q[rr] = 1.0f / fminf(fmaxf(c[rr], 1e-6f), 1e5f);
                    rec[mt][nt] = q;
                }
            if (g == 0) {
                float* outc = out + (size_t)(b * CP) * (X_ * Y_);
#pragma unroll
                for (int mt = 0; mt < 4; ++mt)
#pragma unroll
                    for (int nt = 0; nt < 2; ++nt) {
                        int xg = x0 + (wn * 2 + nt) * 16 + lrow;
                        int yg = y0 + (wm * 4 + mt) * 16 + lkg * 4;
                        *(f32x4*)&outc[(size_t)xg * Y_ + yg] = acc[mt][nt];
                    }
            }
        } else {
            float* outc = out + (size_t)(b * CP + g * 4 + p) * (size_t)(X_ * Y_);
#pragma unroll
            for (int mt = 0; mt < 4; ++mt)
#pragma unroll
                for (int nt = 0; nt < 2; ++nt) {
                    int xg = x0 + (wn * 2 + nt) * 16 + lrow;
                    int yg = y0 + (wm * 4 + mt) * 16 + lkg * 4;
                    f32x4 v = acc[mt][nt] * rec[mt][nt];
                    *(f32x4*)&outc[(size_t)xg * Y_ + yg] = v;
                }
        }
    }
}

extern "C" void kernel_launch(void* const* d_in, const int* in_sizes, int n_in,
                              void* d_out, int out_size, void* d_ws, size_t ws_size,
                              hipStream_t stream)
{
    const float* xin_lon  = (const float*)d_in[0];
    const float* xin_lat  = (const float*)d_in[1];
    const float* wt       = (const float*)d_in[2];
    const float* xout_lon = (const float*)d_in[3];
    const float* xout_lat = (const float*)d_in[4];
    const float* init_ls  = (const float*)d_in[5];
    float* out = (float*)d_out;

    __bf16* wlonT = (__bf16*)d_ws;
    __bf16* wlatT = wlonT + (size_t)B_ * X_ * W_;
    __bf16* wt33  = wlatT + (size_t)B_ * Y_ * H_;
    __bf16* U_T   = wt33 + (size_t)B_ * CP * W_ * H_;

    prep_kernel<<<6272, 256, 0, stream>>>(xin_lon, xin_lat, xout_lon, xout_lat,
                                          init_ls, wt, wlonT, wlatT, wt33);
    gemm_u<<<B_ * CP * 8, 256, 0, stream>>>(wt33, wlatT, U_T);
    stage2_fused<<<512, 256, 0, stream>>>(wlonT, U_T, out);
}